// Round 13
// baseline (284.709 us; speedup 1.0000x reference)
//
#include <hip/hip_runtime.h>
#include <hip/hip_bf16.h>
#include <stdint.h>

// ScaledDotProductAttention S=4096 D=1024 fp32.
// R19: 4th and final 8-phase attempt; fixes R18's two bugs. (1) M-HALVES
// (128 rows x 64 k) restore the 128B LDS row stride -> R15's zero-conflict
// read pattern (R18's K-halves gave 64B rows = 4-way conflicts, 3.1M measured).
// (2) One 2-load stage EVERY phase via stagger-wrapped retirement (R13 bunched
// stages 2/0/4/2 -> m196-class loss). Ladder per iteration (buf0=T, buf1=T+1):
//   ph1 rd A0 im0-3 ks0+ks1 (8) + B0 ks0 (4) | stg T+1.Bh0   mfma acc[0-3] ks0
//   ph2 rd A0 im4-7 ks0+ks1 (8)              | stg T+1.Bh1   mfma acc[4-7] ks0
//   ph3 rd B0 ks1 (4)                        | stg T+2.Ah0   mfma acc[0-3] ks1
//   ph4 (no reads)                           | stg T+2.Ah1   mfma acc[4-7] ks1
//        vmcnt(4)
//   ph5-8: mirror on buf1 (stg T+2.Bh0, T+2.Bh1, T+3.Ah0, T+3.Ah1), vmcnt(4)
// Retire proofs: buf.A last read ph2 (drained ph2 LGKM0 before its end-bar) ->
// ph3/4 stages safe; buf.B last read ph3 -> ph5/6 safe; buf1.A last read ph6 ->
// ph7/8 safe; buf1.B last read ph7 -> next ph1/2 safe. FIFO@ph4: [T+1.A(prev
// ph7,8)=4, T+1.B(ph1,2)=4, T+2.A(ph3,4)=4] -> vmcnt(4) drains T+1 complete
// before ph5 reads it. FIFO@ph8: [T+2.A=4, T+2.B=4, T+3.A=4] -> vmcnt(4)
// drains T+2 before next ph1. Prologue stages T0(8)+T1.A(4), vmcnt(4) = exact
// steady-state entry. Tail (stage off): vmcnt(0). NT=16 even for all GEMMs.
// Epilogues/grids/swizzle verbatim R15 (passed twice).
// (3rd submission: broker died pre-execution twice — same pattern as R16,
// which ran clean on its 3rd submission. No hang/timeout mechanism in kernel.)

typedef __bf16 bf16_t;
typedef __bf16 bf16x4 __attribute__((ext_vector_type(4)));
typedef __bf16 bf16x8 __attribute__((ext_vector_type(8)));
typedef float f32x4 __attribute__((ext_vector_type(4)));

#define AS1 __attribute__((address_space(1)))
#define AS3 __attribute__((address_space(3)))

__device__ __forceinline__ void async_ld16(const void* g, void* l) {
  // global -> LDS DMA, 16B/lane; LDS dest is wave-uniform base + lane*16 by HW rule.
  __builtin_amdgcn_global_load_lds((AS1 void*)g, (AS3 void*)l, 16, 0, 0);
}

#define BAR() __builtin_amdgcn_s_barrier()
#define LGKM0() asm volatile("s_waitcnt lgkmcnt(0)" ::: "memory")
#define VM4() asm volatile("s_waitcnt vmcnt(4)" ::: "memory")
#define VM0() asm volatile("s_waitcnt vmcnt(0)" ::: "memory")

// 256x256 tile, BK=64, 8 waves (2M x 4N), per-wave 128x64 = acc[8][4].
// LDS (dynamic 128KB, elems): A0@0 B0@16384 A1@32768 B1@49152; each A/B is
// [256][64] with two M-halves of 128 rows (8192 elems each).
// MODE 0: QKV epilogue (bias; Q scaled 1/32; V transposed via LDS).
// MODE 1: S epilogue: store exp(acc) bf16 ldc=4096, atomicAdd fp32 row sums.
// MODE 2: O epilogue: zz<3 -> bf16 partial; zz==3 -> fp32 to fout (1/rowsum).
template <int MODE>
__global__ __launch_bounds__(512, 2) void gemm8q(
    const bf16_t* __restrict__ A, const bf16_t* __restrict__ B, const int ld,
    const int Klen, bf16_t* __restrict__ o0, bf16_t* __restrict__ o1,
    bf16_t* __restrict__ o2, const float* __restrict__ b0,
    const float* __restrict__ b1, const float* __restrict__ b2,
    float* __restrict__ fout, float* __restrict__ rowsum) {
  extern __shared__ bf16_t smem[];  // 131072 B

  const int t = threadIdx.x;
  const int lane = t & 63;
  const int wave = t >> 6;
  const int wm = wave >> 2;   // 0..1  (M half: 128 rows)
  const int wn = wave & 3;    // 0..3  (N quarter: 64 cols)
  const int q = lane >> 4;
  const int l16 = lane & 15;
  const int xf = l16 & 7;

  // Grid decode: XCD-aware (bid&7 = XCD), bijective per mode (R15-proven).
  int m0, n0, k0 = 0, zz = 0;
  const int bid = blockIdx.x;
  if constexpr (MODE == 0) {
    const int x = bid & 7, sl = bid >> 3;  // 192 blocks = 16m x 12n
    m0 = ((x >> 1) * 4 + (sl & 3)) * 256;
    n0 = ((x & 1) * 6 + (sl >> 2)) * 256;
  } else if constexpr (MODE == 1) {
    const int x = bid & 7, sl = bid >> 3;  // 256 blocks = 16m x 16n
    m0 = ((x >> 2) * 8 + (sl >> 2)) * 256;
    n0 = ((x & 3) * 4 + (sl & 3)) * 256;
  } else {
    const int x = bid & 7, sl = bid >> 3;  // 256 blocks: 4z x 8m x 4n
    zz = x >> 1;
    m0 = ((x & 1) * 8 + (sl >> 2)) * 256;
    n0 = (sl & 3) * 256;
    k0 = zz * Klen;
  }

  // Staging swizzle (R5/R15-proven, conflict-free): GLOBAL chunk = slot ^
  // (srow&7); LDS linear. One M-half (128 rows x 64 k) = 2 loads of 64 rows.
  const int srow = t >> 3;                      // 0..63
  const int c8s = ((t & 7) ^ (srow & 7)) * 8;
  const bf16_t* Ab = A + (size_t)(m0 + srow) * ld + k0 + c8s;
  const bf16_t* Bb = B + (size_t)(n0 + srow) * ld + k0 + c8s;
  const int tl8 = t * 8;

  bf16_t* A0 = smem;
  bf16_t* B0 = smem + 16384;
  bf16_t* A1 = smem + 32768;
  bf16_t* B1s = smem + 49152;

  // Read-side (R15-verbatim): frag (im,s) at row wm*128+im*16+l16, slot
  // ((s*4+q)^xf); row stride 64 elems = 128B (32-bank wrap, 0 conflicts).
  const int aoff = (wm * 128 + l16) * 64;
  const int boff = (wn * 64 + l16) * 64;
  const int c0 = (q ^ xf) * 8;
  const int c1 = ((4 + q) ^ xf) * 8;

  f32x4 acc[8][4];
  const f32x4 zero4 = {0.f, 0.f, 0.f, 0.f};
#pragma unroll
  for (int i = 0; i < 8; ++i)
#pragma unroll
    for (int j = 0; j < 4; ++j) acc[i][j] = zero4;

  const int NT = Klen >> 6;  // 16 (even) for all three GEMMs

  // Stage one M-half (h) of tile `tile` into lbuf (A or B side via gb).
  auto STG = [&](const bf16_t* gb, bf16_t* lbuf, int tile, int h) {
    const int ko = tile << 6;
    async_ld16(gb + (size_t)(h * 128) * ld + ko, lbuf + h * 8192 + tl8);
    async_ld16(gb + (size_t)(h * 128 + 64) * ld + ko,
               lbuf + h * 8192 + 4096 + tl8);
  };

  // Prologue: T0 complete (8 loads) + T1.A (4 loads); vmcnt(4) drains T0.
  STG(Ab, A0, 0, 0); STG(Ab, A0, 0, 1);
  STG(Bb, B0, 0, 0); STG(Bb, B0, 0, 1);
  STG(Ab, A1, 1, 0); STG(Ab, A1, 1, 1);
  VM4();
  BAR();

  for (int it = 0; it < NT / 2; ++it) {
    const int Tp1 = 2 * it + 1, Tp2 = 2 * it + 2, Tp3 = 2 * it + 3;
    const bool s2 = Tp2 < NT, s3 = Tp3 < NT;
    bf16x8 faA[4][2], faB[4][2], fb[4][2];

#define MM(fa_, ks_, base_)                                                  \
  __builtin_amdgcn_s_setprio(1);                                             \
  _Pragma("unroll") for (int im = 0; im < 4; ++im)                           \
      _Pragma("unroll") for (int j = 0; j < 4; ++j)                          \
          acc[(base_) + im][j] = __builtin_amdgcn_mfma_f32_16x16x32_bf16(    \
              fa_[im][ks_], fb[j][ks_], acc[(base_) + im][j], 0, 0, 0);      \
  __builtin_amdgcn_s_setprio(0);

    // ---- ph1: rd A0 im0-3 (both ks) + B0 ks0; stg T+1.Bh0.
#pragma unroll
    for (int im = 0; im < 4; ++im) {
      faA[im][0] = *(const bf16x8*)(A0 + aoff + im * 1024 + c0);
      faA[im][1] = *(const bf16x8*)(A0 + aoff + im * 1024 + c1);
    }
#pragma unroll
    for (int j = 0; j < 4; ++j)
      fb[j][0] = *(const bf16x8*)(B0 + boff + j * 1024 + c0);
    STG(Bb, B1s, Tp1, 0);
    BAR(); LGKM0();
    MM(faA, 0, 0);
    BAR();

    // ---- ph2: rd A0 im4-7 (both ks); stg T+1.Bh1.
#pragma unroll
    for (int im = 0; im < 4; ++im) {
      faB[im][0] = *(const bf16x8*)(A0 + aoff + (im + 4) * 1024 + c0);
      faB[im][1] = *(const bf16x8*)(A0 + aoff + (im + 4) * 1024 + c1);
    }
    STG(Bb, B1s, Tp1, 1);
    BAR(); LGKM0();
    MM(faB, 0, 4);
    BAR();

    // ---- ph3: rd B0 ks1; stg T+2.Ah0 (buf0.A retired ph2).
#pragma unroll
    for (int j = 0; j < 4; ++j)
      fb[j][1] = *(const bf16x8*)(B0 + boff + j * 1024 + c1);
    if (s2) STG(Ab, A0, Tp2, 0);
    BAR(); LGKM0();
    MM(faA, 1, 0);
    BAR();

    // ---- ph4: stg T+2.Ah1; counted vmcnt (drains T+1 complete).
    if (s2) STG(Ab, A0, Tp2, 1);
    MM(faB, 1, 4);
    if (s2) { VM4(); } else { VM0(); }
    BAR();

    // ---- ph5: rd A1 im0-3 (both ks) + B1 ks0; stg T+2.Bh0 (buf0.B dead ph3).
#pragma unroll
    for (int im = 0; im < 4; ++im) {
      faA[im][0] = *(const bf16x8*)(A1 + aoff + im * 1024 + c0);
      faA[im][1] = *(const bf16x8*)(A1 + aoff + im * 1024 + c1);
    }
#pragma unroll
    for (int j = 0; j < 4; ++j)
      fb[j][0] = *(const bf16x8*)(B1s + boff + j * 1024 + c0);
    if (s2) STG(Bb, B0, Tp2, 0);
    BAR(); LGKM0();
    MM(faA, 0, 0);
    BAR();

    // ---- ph6: rd A1 im4-7 (both ks); stg T+2.Bh1.
#pragma unroll
    for (int im = 0; im < 4; ++im) {
      faB[im][0] = *(const bf16x8*)(A1 + aoff + (im + 4) * 1024 + c0);
      faB[im][1] = *(const bf16x8*)(A1 + aoff + (im + 4) * 1024 + c1);
    }
    if (s2) STG(Bb, B0, Tp2, 1);
    BAR(); LGKM0();
    MM(faB, 0, 4);
    BAR();

    // ---- ph7: rd B1 ks1; stg T+3.Ah0 (buf1.A retired ph6).
#pragma unroll
    for (int j = 0; j < 4; ++j)
      fb[j][1] = *(const bf16x8*)(B1s + boff + j * 1024 + c1);
    if (s3) STG(Ab, A1, Tp3, 0);
    BAR(); LGKM0();
    MM(faA, 1, 0);
    BAR();

    // ---- ph8: stg T+3.Ah1; counted vmcnt (drains T+2 complete).
    if (s3) STG(Ab, A1, Tp3, 1);
    MM(faB, 1, 4);
    if (s3) { VM4(); } else { VM0(); }
    BAR();
#undef MM
  }

  // C/D layout: col = lane&15, row = quad*4 + reg (m89/m91-verified).
  const int mW = m0 + wm * 128 + q * 4;  // + im*16 + r

  if constexpr (MODE == 0) {
    const int sel = n0 >> 10;  // 0=Q 1=K 2=V  (256-tiles never straddle)
    const int nl0 = (n0 & 1023) + wn * 64 + l16;
    if (sel < 2) {
      const float* bias = (sel == 0) ? b0 : b1;
      const float sc = (sel == 0) ? 0.03125f : 1.0f;  // 1/sqrt(1024) in Q
      bf16_t* dst = (sel == 0) ? o0 : o1;
      float bb[4];
#pragma unroll
      for (int j = 0; j < 4; ++j) bb[j] = bias[nl0 + j * 16];
      // j INNERMOST: 4 consecutive stores complete each 128B run (R13 fix).
#pragma unroll
      for (int im = 0; im < 8; ++im) {
        const int mr = mW + im * 16;
#pragma unroll
        for (int r = 0; r < 4; ++r)
#pragma unroll
          for (int j = 0; j < 4; ++j)
            dst[(size_t)(mr + r) * 1024 + nl0 + j * 16] =
                (bf16_t)((acc[im][j][r] + bb[j]) * sc);
      }
    } else {
      // V^T via LDS transpose (R15-verbatim): two passes of 128 d-rows x
      // 256 m; stride 264 elems; 16B/lane drain, 512B contiguous per row.
      bf16_t* vs = smem;  // 128*264*2 = 67584 B (K-loop buffers dead)
      const int dg0 = n0 & 1023;
#pragma unroll
      for (int h = 0; h < 2; ++h) {
        if ((wn >> 1) == h) {
#pragma unroll
          for (int j = 0; j < 4; ++j) {
            const int dl = (wn & 1) * 64 + j * 16 + l16;  // 0..127
            const float bb = b2[dg0 + h * 128 + dl];
#pragma unroll
            for (int im = 0; im < 8; ++im) {
              bf16x4 v;
#pragma unroll
              for (int r = 0; r < 4; ++r) v[r] = (bf16_t)(acc[im][j][r] + bb);
              *(bf16x4*)(vs + dl * 264 + wm * 128 + im * 16 + q * 4) = v;
            }
          }
        }
        __syncthreads();
#pragma unroll
        for (int rr = 0; rr < 8; ++rr) {
          const int task = rr * 512 + t;
          const int row = task >> 5, ck = task & 31;
          *(bf16x8*)(o2 + (size_t)(dg0 + h * 128 + row) * 4096 + m0 + ck * 8) =
              *(const bf16x8*)(vs + row * 264 + ck * 8);
        }
        __syncthreads();
      }
    }
  } else if constexpr (MODE == 1) {
    float ps[8][4];
#pragma unroll
    for (int im = 0; im < 8; ++im)
#pragma unroll
      for (int r = 0; r < 4; ++r) ps[im][r] = 0.f;
    const int nb = n0 + wn * 64 + l16;
    // j INNERMOST: complete 128B runs back-to-back (R13 write-combine fix).
#pragma unroll
    for (int im = 0; im < 8; ++im) {
      const int mr = mW + im * 16;
#pragma unroll
      for (int r = 0; r < 4; ++r)
#pragma unroll
        for (int j = 0; j < 4; ++j) {
          const float e = __expf(acc[im][j][r]);
          ps[im][r] += e;
          o0[(size_t)(mr + r) * 4096 + nb + j * 16] = (bf16_t)e;
        }
    }
#pragma unroll
    for (int im = 0; im < 8; ++im)
#pragma unroll
      for (int r = 0; r < 4; ++r) {
        float v = ps[im][r];
        v += __shfl_xor(v, 1);
        v += __shfl_xor(v, 2);
        v += __shfl_xor(v, 4);
        v += __shfl_xor(v, 8);
        ps[im][r] = v;
      }
    if (l16 == 0) {
#pragma unroll
      for (int im = 0; im < 8; ++im)
#pragma unroll
        for (int r = 0; r < 4; ++r)
          atomicAdd(rowsum + mW + im * 16 + r, ps[im][r]);
    }
  } else {
    float inv[8][4];
#pragma unroll
    for (int im = 0; im < 8; ++im)
#pragma unroll
      for (int r = 0; r < 4; ++r)
        inv[im][r] = 1.0f / rowsum[mW + im * 16 + r];
    const int nb = n0 + wn * 64 + l16;
    if (zz < 3) {  // bf16 partial (normalized); partials over splits sum to O
      bf16_t* pp = (zz == 0) ? o0 : ((zz == 1) ? o1 : o2);
#pragma unroll
      for (int im = 0; im < 8; ++im) {
        const int mr = mW + im * 16;
#pragma unroll
        for (int r = 0; r < 4; ++r) {
          const float iv = inv[im][r];
#pragma unroll
          for (int j = 0; j < 4; ++j)
            pp[(size_t)(mr + r) * 1024 + nb + j * 16] =
                (bf16_t)(acc[im][j][r] * iv);
        }
      }
    } else {  // zz==3: fp32 partial straight into d_out; reduce adds the rest
#pragma unroll
      for (int im = 0; im < 8; ++im) {
        const int mr = mW + im * 16;
#pragma unroll
        for (int r = 0; r < 4; ++r) {
          const float iv = inv[im][r];
#pragma unroll
          for (int j = 0; j < 4; ++j)
            fout[(size_t)(mr + r) * 1024 + nb + j * 16] = acc[im][j][r] * iv;
        }
      }
    }
  }
}

// Converts X|Wq|Wk|Wv to bf16; last 16 blocks zero rowsum (4096 f32).
__global__ __launch_bounds__(256) void cvt_all(
    const float* __restrict__ X, const float* __restrict__ Wq,
    const float* __restrict__ Wk, const float* __restrict__ Wv,
    bf16_t* __restrict__ Xb, bf16_t* __restrict__ Wb,
    float* __restrict__ rowsum) {
  int i = blockIdx.x * 256 + threadIdx.x;
  if (i >= 1835008) {
    rowsum[i - 1835008] = 0.f;
    return;
  }
  const float* src;
  bf16_t* dst;
  int off;
  if (i < 1048576) {
    src = X; dst = Xb; off = i;
  } else {
    const int w = i - 1048576;
    const int sel = w >> 18;
    off = w & 0x3FFFF;
    src = (sel == 0) ? Wq : ((sel == 1) ? Wk : Wv);
    dst = Wb + (size_t)sel * (1024 * 1024);
  }
  const float4 v = ((const float4*)src)[off];
  bf16x4 o;
  o[0] = (bf16_t)v.x; o[1] = (bf16_t)v.y; o[2] = (bf16_t)v.z; o[3] = (bf16_t)v.w;
  ((bf16x4*)dst)[off] = o;
}

// out[i] += f32(p0[i]) + f32(p1[i]) + f32(p2[i]);  8 elems/thread.
__global__ __launch_bounds__(256) void reduce_out(
    const bf16_t* __restrict__ p0, const bf16_t* __restrict__ p1,
    const bf16_t* __restrict__ p2, float* __restrict__ out) {
  const int i = blockIdx.x * 256 + threadIdx.x;
  const bf16x8 a = ((const bf16x8*)p0)[i];
  const bf16x8 b = ((const bf16x8*)p1)[i];
  const bf16x8 c = ((const bf16x8*)p2)[i];
  float4 lo = ((const float4*)out)[2 * i];
  float4 hi = ((const float4*)out)[2 * i + 1];
  lo.x += (float)a[0] + (float)b[0] + (float)c[0];
  lo.y += (float)a[1] + (float)b[1] + (float)c[1];
  lo.z += (float)a[2] + (float)b[2] + (float)c[2];
  lo.w += (float)a[3] + (float)b[3] + (float)c[3];
  hi.x += (float)a[4] + (float)b[4] + (float)c[4];
  hi.y += (float)a[5] + (float)b[5] + (float)c[5];
  hi.z += (float)a[6] + (float)b[6] + (float)c[6];
  hi.w += (float)a[7] + (float)b[7] + (float)c[7];
  ((float4*)out)[2 * i] = lo;
  ((float4*)out)[2 * i + 1] = hi;
}

extern "C" void kernel_launch(void* const* d_in, const int* in_sizes, int n_in,
                              void* d_out, int out_size, void* d_ws,
                              size_t ws_size, hipStream_t stream) {
  const int S = 4096, D = 1024;
  const float* X  = (const float*)d_in[0];
  const float* Wq = (const float*)d_in[1];
  const float* bq = (const float*)d_in[2];
  const float* Wk = (const float*)d_in[3];
  const float* bk = (const float*)d_in[4];
  const float* Wv = (const float*)d_in[5];
  const float* bv = (const float*)d_in[6];
  float* out = (float*)d_out;

  // ws layout (70 MB bf16 + 16 KB fp32). G3 split-K=4 partials reuse dead
  // regions: Xb (dead after G1), Qb, Kb (dead after G2); z=3 goes to d_out.
  bf16_t* Xb = (bf16_t*)d_ws;            // [4096][1024]
  bf16_t* Wb = Xb + (size_t)S * D;       // [3072][1024]
  bf16_t* Qb = Wb + (size_t)3 * D * D;   // [4096][1024], pre-scaled by 1/32
  bf16_t* Kb = Qb + (size_t)S * D;       // [4096][1024]
  bf16_t* Vt = Kb + (size_t)S * D;       // [1024][4096]  V transposed
  bf16_t* Sc = Vt + (size_t)D * S;       // [4096][4096]  exp(scores)
  float* rowsum = (float*)(Sc + (size_t)S * S);  // [4096]

  // 128 KiB dynamic LDS opt-in (idempotent; capture-safe — ran fine R15/R18).
  static int attr_set = 0;
  if (!attr_set) {
    attr_set = 1;
    (void)hipFuncSetAttribute(reinterpret_cast<const void*>(gemm8q<0>),
                              hipFuncAttributeMaxDynamicSharedMemorySize,
                              131072);
    (void)hipFuncSetAttribute(reinterpret_cast<const void*>(gemm8q<1>),
                              hipFuncAttributeMaxDynamicSharedMemorySize,
                              131072);
    (void)hipFuncSetAttribute(reinterpret_cast<const void*>(gemm8q<2>),
                              hipFuncAttributeMaxDynamicSharedMemorySize,
                              131072);
  }

  cvt_all<<<7184, 256, 0, stream>>>(X, Wq, Wk, Wv, Xb, Wb, rowsum);

  // G1: QKV = Xb @ Wb^T + bias  (M=4096, N=3072, K=1024), 192 blocks
  gemm8q<0><<<192, 512, 131072, stream>>>(
      Xb, Wb, D, D, Qb, Kb, Vt, bq, bk, bv, nullptr, nullptr);
  // G2: Sc = exp(Qb @ Kb^T), rowsum partials  (M=N=4096, K=1024), 256 blocks
  gemm8q<1><<<256, 512, 131072, stream>>>(
      Qb, Kb, D, D, Sc, nullptr, nullptr, nullptr, nullptr, nullptr, nullptr,
      rowsum);
  // G3: O-partials = (Sc @ Vt^T)/rowsum, K split 4x1024, 256 blocks
  gemm8q<2><<<256, 512, 131072, stream>>>(
      Sc, Vt, S, S / 4, Xb, Qb, Kb, nullptr, nullptr, nullptr, out, rowsum);
  // out += p0 + p1 + p2
  reduce_out<<<S * D / 8 / 256, 256, 0, stream>>>(Xb, Qb, Kb, out);
}